// Round 1
// baseline (246.262 us; speedup 1.0000x reference)
//
#include <hip/hip_runtime.h>

#define N_IMG 4
#define E_DIM 16
#define P_PIX 320000
#define C_CLS 20
#define CK 19            // C - 1 (IGNORE = 0 excluded)
#define LDS_STRIDE 17    // pad so 20 labels scatter across 32 banks

// ws layout (floats):
//   [0,    1280) sums[n][c][e]
//   [1280, 1360) counts[n][c]
//   [1360, 2640) means[n][c][e]
//   [2640]       loss accumulator
#define SUMS_OFF 0
#define CNT_OFF  (N_IMG * C_CLS * E_DIM)            // 1280
#define MEAN_OFF (CNT_OFF + N_IMG * C_CLS)          // 1360
#define LOSS_OFF (MEAN_OFF + N_IMG * C_CLS * E_DIM) // 2640
#define WS_FLOATS (LOSS_OFF + 1)

// ---------------- Kernel 1: per-class sums + counts ----------------
__global__ void k_sums(const float* __restrict__ emb, const int* __restrict__ target,
                       float* __restrict__ ws) {
    __shared__ float lsum[C_CLS * LDS_STRIDE];
    __shared__ float lcnt[C_CLS];
    const int tid = threadIdx.x;
    const int n = blockIdx.y;

    for (int i = tid; i < C_CLS * LDS_STRIDE; i += blockDim.x) lsum[i] = 0.f;
    if (tid < C_CLS) lcnt[tid] = 0.f;
    __syncthreads();

    const float* embn = emb + (size_t)n * E_DIM * P_PIX;
    const int*   tgtn = target + (size_t)n * P_PIX;
    const int stride = gridDim.x * blockDim.x;

    for (int p = blockIdx.x * blockDim.x + tid; p < P_PIX; p += stride) {
        const int lab = tgtn[p];
        atomicAdd(&lcnt[lab], 1.0f);
        const int base = lab * LDS_STRIDE;
#pragma unroll
        for (int e = 0; e < E_DIM; e++) {
            atomicAdd(&lsum[base + e], embn[(size_t)e * P_PIX + p]);
        }
    }
    __syncthreads();

    float* gsum = ws + SUMS_OFF + n * C_CLS * E_DIM;
    float* gcnt = ws + CNT_OFF + n * C_CLS;
    for (int i = tid; i < C_CLS * E_DIM; i += blockDim.x) {
        const int c = i / E_DIM, e = i % E_DIM;
        atomicAdd(&gsum[i], lsum[c * LDS_STRIDE + e]);
    }
    if (tid < C_CLS) atomicAdd(&gcnt[tid], lcnt[tid]);
}

// -------- Kernel 2: means + distance(push) term + regularizer --------
__global__ void k_means_dist(float* __restrict__ ws) {
    __shared__ float lmean[C_CLS * E_DIM];
    __shared__ float red[256];
    const int n = blockIdx.x, tid = threadIdx.x;

    const float* gsum = ws + SUMS_OFF + n * C_CLS * E_DIM;
    const float* gcnt = ws + CNT_OFF + n * C_CLS;
    float* gmean = ws + MEAN_OFF + n * C_CLS * E_DIM;

    for (int i = tid; i < C_CLS * E_DIM; i += blockDim.x) {
        const int c = i / E_DIM;
        const float cnt = gcnt[c];
        const float m = (cnt > 0.f) ? gsum[i] / cnt : 0.f;
        lmean[i] = m;
        gmean[i] = m;
    }
    __syncthreads();

    float acc = 0.f;
    // pairwise hinge over kept classes (1..19), both orders, diag excluded
    for (int idx = tid; idx < CK * CK; idx += blockDim.x) {
        const int i = idx / CK + 1, j = idx % CK + 1;
        if (i != j) {
            float sq = 0.f;
#pragma unroll
            for (int e = 0; e < E_DIM; e++) {
                const float d = lmean[i * E_DIM + e] - lmean[j * E_DIM + e];
                sq += d * d;
            }
            const float dm = sqrtf(sq);
            const float h = fmaxf(3.0f - dm, 0.f);   // 2*DELTA_DIST = 3
            acc += h * h;
        }
    }
    acc *= 1.0f / (float)(CK * (CK - 1));            // BETA = 1

    // regularizer: mean norm of kept means
    float racc = 0.f;
    for (int c = tid + 1; c < C_CLS; c += blockDim.x) {
        float sq = 0.f;
#pragma unroll
        for (int e = 0; e < E_DIM; e++) {
            const float m = lmean[c * E_DIM + e];
            sq += m * m;
        }
        racc += sqrtf(sq);
    }
    acc += 0.001f * racc / (float)CK;                // GAMMA = 0.001

    red[tid] = acc;
    __syncthreads();
    for (int s = blockDim.x / 2; s > 0; s >>= 1) {
        if (tid < s) red[tid] += red[tid + s];
        __syncthreads();
    }
    if (tid == 0) atomicAdd(ws + LOSS_OFF, red[0]);
}

// ---------------- Kernel 3: variance (pull) term ----------------
__global__ void k_var(const float* __restrict__ emb, const int* __restrict__ target,
                      float* __restrict__ ws) {
    __shared__ float lmean[C_CLS * LDS_STRIDE];
    __shared__ float lw[C_CLS];
    __shared__ float red[256];
    const int tid = threadIdx.x, n = blockIdx.y;

    const float* gmean = ws + MEAN_OFF + n * C_CLS * E_DIM;
    const float* gcnt = ws + CNT_OFF + n * C_CLS;
    for (int i = tid; i < C_CLS * E_DIM; i += blockDim.x) {
        const int c = i / E_DIM, e = i % E_DIM;
        lmean[c * LDS_STRIDE + e] = gmean[i];
    }
    if (tid < C_CLS) {
        const float cnt = gcnt[tid];
        lw[tid] = (cnt > 0.f) ? 1.0f / (cnt * (float)CK) : 0.f;
    }
    __syncthreads();

    const float* embn = emb + (size_t)n * E_DIM * P_PIX;
    const int*   tgtn = target + (size_t)n * P_PIX;
    const int stride = gridDim.x * blockDim.x;

    float acc = 0.f;
    for (int p = blockIdx.x * blockDim.x + tid; p < P_PIX; p += stride) {
        const int lab = tgtn[p];
        if (lab != 0) {
            const int base = lab * LDS_STRIDE;
            float sq = 0.f;
#pragma unroll
            for (int e = 0; e < E_DIM; e++) {
                const float d = embn[(size_t)e * P_PIX + p] - lmean[base + e];
                sq += d * d;
            }
            const float dd = sqrtf(sq);
            const float h = fmaxf(dd - 0.5f, 0.f);   // DELTA_VAR = 0.5
            acc += h * h * lw[lab];                  // ALPHA = 1
        }
    }

    red[tid] = acc;
    __syncthreads();
    for (int s = blockDim.x / 2; s > 0; s >>= 1) {
        if (tid < s) red[tid] += red[tid + s];
        __syncthreads();
    }
    if (tid == 0) atomicAdd(ws + LOSS_OFF, red[0]);
}

// ---------------- Kernel 4: finalize ----------------
__global__ void k_fin(const float* __restrict__ ws, float* __restrict__ out) {
    out[0] = ws[LOSS_OFF] * 0.25f;  // mean over 4 images
}

extern "C" void kernel_launch(void* const* d_in, const int* in_sizes, int n_in,
                              void* d_out, int out_size, void* d_ws, size_t ws_size,
                              hipStream_t stream) {
    const float* emb = (const float*)d_in[0];
    const int* target = (const int*)d_in[1];
    float* out = (float*)d_out;
    float* ws = (float*)d_ws;

    hipMemsetAsync(d_ws, 0, WS_FLOATS * sizeof(float), stream);

    dim3 grid1(256, N_IMG);
    k_sums<<<grid1, 256, 0, stream>>>(emb, target, ws);
    k_means_dist<<<N_IMG, 256, 0, stream>>>(ws);
    k_var<<<grid1, 256, 0, stream>>>(emb, target, ws);
    k_fin<<<1, 1, 0, stream>>>(ws, out);
}